// Round 13
// baseline (364.606 us; speedup 1.0000x reference)
//
#include <hip/hip_runtime.h>
#include <hip/hip_bf16.h>

// Sizes (fixed by the problem)
#define T_ 1024
#define S_ 1024
#define B_ 4
#define D_ 1024
#define H_ 16
#define DH_ 64
#define DI_ 4096
#define NTOK 4096          // T*B

typedef __attribute__((ext_vector_type(8))) short bf16x8;
typedef __attribute__((ext_vector_type(4))) float f32x4;

__device__ __forceinline__ short f2bf(float f) {
  unsigned u = __builtin_bit_cast(unsigned, f);
  u += 0x7fffu + ((u >> 16) & 1u);
  return (short)(u >> 16);
}

__device__ __forceinline__ void g2l16(const void* g, void* l) {
  __builtin_amdgcn_global_load_lds(
      (const __attribute__((address_space(1))) unsigned int*)g,
      (__attribute__((address_space(3))) unsigned int*)l, 16, 0, 0);
}

__device__ __forceinline__ void bar() {
  asm volatile("" ::: "memory");
  __builtin_amdgcn_s_barrier();
  asm volatile("" ::: "memory");
}

// ---------------------------------------------------------------------------
// 8-phase 256x256 GEMM (T2+T3+T4+T5) for FFN1 (grid 16x16 = 256 blocks).
// bv0 (nh0 B-frags) stays live ph0->ph3 (round-12: LDS reads 28KB -> 24KB).
// ---------------------------------------------------------------------------
template <int EPI>
__global__ __launch_bounds__(512, 2) void gemm8p(
    const short* __restrict__ A, const short* __restrict__ Bt,
    float* __restrict__ outF, short* __restrict__ outB,
    const float* __restrict__ res, const float* __restrict__ bias,
    int M, int N, int K) {
  __shared__ short sA[2][256 * 64];
  __shared__ short sB[2][256 * 64];
  const int tid = threadIdx.x;
  const int lane = tid & 63;
  const int w = tid >> 6;            // 0..7
  const int wm = w >> 2, wn = w & 3; // 2M x 4N wave grid
  const int r15 = lane & 15, g4 = lane >> 4;
  const size_t row0 = (size_t)blockIdx.x * 256;
  const size_t col0 = (size_t)blockIdx.y * 256;

  f32x4 acc[8][4];
#pragma unroll
  for (int i = 0; i < 8; i++)
#pragma unroll
    for (int j = 0; j < 4; j++) acc[i][j] = (f32x4){0.f, 0.f, 0.f, 0.f};

  auto stageA = [&](int buf, int s, int kt) {
    const int k0 = kt << 6;
#pragma unroll
    for (int j = 0; j < 2; ++j) {
      const int c = j * 8 + w;
      const int rb = ((c >> 3) << 7) + (s << 6) + ((c & 7) << 3);
      const int row = rb + (lane >> 3);
      const int col = k0 + (((lane & 7) ^ (row & 7)) << 3);
      g2l16(A + (row0 + row) * (size_t)K + col, &sA[buf][rb * 64]);
    }
  };
  auto stageB = [&](int buf, int s, int kt) {
    const int k0 = kt << 6;
#pragma unroll
    for (int j = 0; j < 2; ++j) {
      const int c = j * 8 + w;
      const int rb = ((c >> 2) << 6) + (s << 5) + ((c & 3) << 3);
      const int row = rb + (lane >> 3);
      const int col = k0 + (((lane & 7) ^ (row & 7)) << 3);
      g2l16(Bt + (col0 + row) * (size_t)K + col, &sB[buf][rb * 64]);
    }
  };

  const int nk = K >> 6;
  stageA(0, 0, 0); stageA(0, 1, 0); stageB(0, 0, 0); stageB(0, 1, 0);
  if (nk > 1) {
    stageA(1, 0, 1); stageB(1, 1, 1);
    asm volatile("s_waitcnt vmcnt(4)" ::: "memory");
  } else {
    asm volatile("s_waitcnt vmcnt(0)" ::: "memory");
  }
  bar();

  bf16x8 af[4][2], bv0[2][2], bv1[2][2];
  for (int t = 0; t < nk; ++t) {
    const int cur = t & 1;
    const short* cA = sA[cur];
    const short* cB = sB[cur];
    // phase 0: (mh0, nh0); stage A-S1(t+1)
#pragma unroll
    for (int mi = 0; mi < 4; mi++) {
      const int rowA = wm * 128 + mi * 16 + r15;
#pragma unroll
      for (int kk = 0; kk < 2; kk++)
        af[mi][kk] = *(const bf16x8*)(cA + rowA * 64 +
                                      (((kk * 4 + g4) ^ (rowA & 7)) << 3));
    }
#pragma unroll
    for (int ni = 0; ni < 2; ni++) {
      const int rowB = wn * 64 + ni * 16 + r15;
#pragma unroll
      for (int kk = 0; kk < 2; kk++)
        bv0[ni][kk] = *(const bf16x8*)(cB + rowB * 64 +
                                       (((kk * 4 + g4) ^ (rowB & 7)) << 3));
    }
    if (t + 1 < nk) stageA(cur ^ 1, 1, t + 1);
    bar();
    asm volatile("s_waitcnt lgkmcnt(0)" ::: "memory");
    __builtin_amdgcn_s_setprio(1);
#pragma unroll
    for (int kk = 0; kk < 2; kk++)
#pragma unroll
      for (int mi = 0; mi < 4; mi++)
#pragma unroll
        for (int ni = 0; ni < 2; ni++)
          acc[mi][ni] = __builtin_amdgcn_mfma_f32_16x16x32_bf16(
              af[mi][kk], bv0[ni][kk], acc[mi][ni], 0, 0, 0);
    __builtin_amdgcn_s_setprio(0);
    bar();
    // phase 1: (mh0, nh1), af reused; stage B-S0(t+1)
#pragma unroll
    for (int ni = 0; ni < 2; ni++) {
      const int rowB = wn * 64 + (2 + ni) * 16 + r15;
#pragma unroll
      for (int kk = 0; kk < 2; kk++)
        bv1[ni][kk] = *(const bf16x8*)(cB + rowB * 64 +
                                       (((kk * 4 + g4) ^ (rowB & 7)) << 3));
    }
    if (t + 1 < nk) stageB(cur ^ 1, 0, t + 1);
    bar();
    asm volatile("s_waitcnt lgkmcnt(0)" ::: "memory");
    __builtin_amdgcn_s_setprio(1);
#pragma unroll
    for (int kk = 0; kk < 2; kk++)
#pragma unroll
      for (int mi = 0; mi < 4; mi++)
#pragma unroll
        for (int ni = 0; ni < 2; ni++)
          acc[mi][2 + ni] = __builtin_amdgcn_mfma_f32_16x16x32_bf16(
              af[mi][kk], bv1[ni][kk], acc[mi][2 + ni], 0, 0, 0);
    __builtin_amdgcn_s_setprio(0);
    bar();
    // phase 2: (mh1, nh1), bv1 reused; stage A-S0(t+2)
#pragma unroll
    for (int mi = 0; mi < 4; mi++) {
      const int rowA = wm * 128 + (4 + mi) * 16 + r15;
#pragma unroll
      for (int kk = 0; kk < 2; kk++)
        af[mi][kk] = *(const bf16x8*)(cA + rowA * 64 +
                                      (((kk * 4 + g4) ^ (rowA & 7)) << 3));
    }
    if (t + 2 < nk) stageA(cur, 0, t + 2);
    bar();
    asm volatile("s_waitcnt lgkmcnt(0)" ::: "memory");
    __builtin_amdgcn_s_setprio(1);
#pragma unroll
    for (int kk = 0; kk < 2; kk++)
#pragma unroll
      for (int mi = 0; mi < 4; mi++)
#pragma unroll
        for (int ni = 0; ni < 2; ni++)
          acc[4 + mi][2 + ni] = __builtin_amdgcn_mfma_f32_16x16x32_bf16(
              af[mi][kk], bv1[ni][kk], acc[4 + mi][2 + ni], 0, 0, 0);
    __builtin_amdgcn_s_setprio(0);
    bar();
    // phase 3: (mh1, nh0), af + bv0 reused; stage B-S1(t+2)
    if (t + 2 < nk) stageB(cur, 1, t + 2);
    bar();
    asm volatile("s_waitcnt lgkmcnt(0)" ::: "memory");
    __builtin_amdgcn_s_setprio(1);
#pragma unroll
    for (int kk = 0; kk < 2; kk++)
#pragma unroll
      for (int mi = 0; mi < 4; mi++)
#pragma unroll
        for (int ni = 0; ni < 2; ni++)
          acc[4 + mi][ni] = __builtin_amdgcn_mfma_f32_16x16x32_bf16(
              af[mi][kk], bv0[ni][kk], acc[4 + mi][ni], 0, 0, 0);
    __builtin_amdgcn_s_setprio(0);
    if (t + 2 < nk)
      asm volatile("s_waitcnt vmcnt(4)" ::: "memory");
    else if (t + 1 < nk)
      asm volatile("s_waitcnt vmcnt(0)" ::: "memory");
    bar();
  }

#pragma unroll
  for (int mi = 0; mi < 8; mi++) {
    size_t row = row0 + wm * 128 + mi * 16 + (g4 << 2);
#pragma unroll
    for (int ni = 0; ni < 4; ni++) {
      size_t col = col0 + wn * 64 + ni * 16 + r15;
      float bcol = (EPI == 2 || EPI == 3) ? bias[col] : 0.f;
#pragma unroll
      for (int r = 0; r < 4; r++) {
        size_t idx = (row + r) * (size_t)N + col;
        float v = acc[mi][ni][r];
        if (EPI == 0) {
          outB[idx] = f2bf(v);
        } else if (EPI == 1) {
          outF[idx] = v + res[idx];
        } else if (EPI == 2) {
          float x = v + bcol;
          float gl = 0.5f * x * (1.f + erff(x * 0.70710678118654752f));
          outB[idx] = f2bf(gl);
        } else {
          outF[idx] = v + bcol + res[idx];
        }
      }
    }
  }
}

// ---------------------------------------------------------------------------
// 2-phase GEMM, 128xBN tile. Kst = row stride of A/Bt; Kloop = K extent this
// block accumulates (split-K: blockIdx.z picks the K-half and the fp32
// partial plane). EPI 1: outF=acc+res; 5: outF(partial plane)=acc.
// BN=64: LDS 48KB; split-K grid 1024 -> 3 blocks/CU.
// ---------------------------------------------------------------------------
template <int EPI, int BN>
__global__ __launch_bounds__(256, 2) void gemm_bt(
    const short* __restrict__ A, const short* __restrict__ Bt,
    float* __restrict__ outF, short* __restrict__ outB,
    const float* __restrict__ res, const float* __restrict__ bias,
    int M, int N, int Kst, int Kloop) {
  constexpr int WCOLS = BN / 64;
  constexpr int MI = (WCOLS == 2) ? 4 : 2;
  constexpr int BLOADS = BN / 32;
  __shared__ short sA[2][128 * 64];
  __shared__ short sB[2][BN * 64];
  const int tid = threadIdx.x;
  const int lane = tid & 63;
  const int w = tid >> 6;
  const int wr = (WCOLS == 2) ? (w >> 1) : w;
  const int wc = (WCOLS == 2) ? (w & 1) : 0;
  const int r15 = lane & 15, g4 = lane >> 4;
  const size_t row0 = (size_t)blockIdx.x * 128;
  const size_t col0 = (size_t)blockIdx.y * BN;
  const int kOff = (EPI == 5) ? blockIdx.z * Kloop : 0;
  float* outP = (EPI == 5) ? outF + (size_t)blockIdx.z * M * (size_t)N : outF;

  f32x4 acc[MI][4];
#pragma unroll
  for (int i = 0; i < MI; i++)
#pragma unroll
    for (int j = 0; j < 4; j++) acc[i][j] = (f32x4){0.f, 0.f, 0.f, 0.f};

  auto stage = [&](int buf, int kt) {
    const int k0 = kOff + (kt << 6);
#pragma unroll
    for (int i = 0; i < 4; i++) {
      int flat = i * 256 + tid;
      int row = flat >> 3;
      int col = k0 + (((flat & 7) ^ (row & 7)) << 3);
      g2l16(A + (row0 + row) * (size_t)Kst + col, &sA[buf][(i * 256 + w * 64) * 8]);
    }
#pragma unroll
    for (int i = 0; i < BLOADS; i++) {
      int flat = i * 256 + tid;
      int row = flat >> 3;
      int col = k0 + (((flat & 7) ^ (row & 7)) << 3);
      g2l16(Bt + (col0 + row) * (size_t)Kst + col, &sB[buf][(i * 256 + w * 64) * 8]);
    }
  };

  stage(0, 0);
  __syncthreads();

  const int nk = Kloop >> 6;
  for (int kt = 0; kt < nk; ++kt) {
    const int cur = kt & 1;
    if (kt + 1 < nk) stage(cur ^ 1, kt + 1);
#pragma unroll
    for (int kk = 0; kk < 2; ++kk) {
      bf16x8 af[MI], bfr[4];
#pragma unroll
      for (int mi = 0; mi < MI; mi++) {
        int rowA = wr * (MI * 16) + mi * 16 + r15;
        af[mi] = *(const bf16x8*)(&sA[cur][rowA * 64 +
                                           (((kk * 4 + g4) ^ (rowA & 7)) << 3)]);
      }
#pragma unroll
      for (int ni = 0; ni < 4; ni++) {
        int rowB = wc * 64 + ni * 16 + r15;
        bfr[ni] = *(const bf16x8*)(&sB[cur][rowB * 64 +
                                            (((kk * 4 + g4) ^ (rowB & 7)) << 3)]);
      }
#pragma unroll
      for (int mi = 0; mi < MI; mi++)
#pragma unroll
        for (int ni = 0; ni < 4; ni++)
          acc[mi][ni] = __builtin_amdgcn_mfma_f32_16x16x32_bf16(af[mi], bfr[ni],
                                                                acc[mi][ni], 0, 0, 0);
    }
    __syncthreads();
  }

#pragma unroll
  for (int mi = 0; mi < MI; mi++) {
    size_t row = row0 + wr * (MI * 16) + mi * 16 + (g4 << 2);
#pragma unroll
    for (int ni = 0; ni < 4; ni++) {
      size_t col = col0 + wc * 64 + ni * 16 + r15;
#pragma unroll
      for (int r = 0; r < 4; r++) {
        size_t idx = (row + r) * (size_t)N + col;
        float v = acc[mi][ni][r];
        if (EPI == 1) {
          outF[idx] = v + res[idx];
        } else if (EPI == 5) {
          outP[idx] = v;
        } else {
          outF[idx] = v + res[idx];
        }
      }
    }
  }
}

// FFN2 combine: out = P0 + P1 + bias + res   (4096 rows x 1024 cols)
__global__ __launch_bounds__(256) void ffn2_fin(const float* __restrict__ P,
                                                const float* __restrict__ res,
                                                const float* __restrict__ bias,
                                                float* __restrict__ out) {
  const int row = blockIdx.x, tid = threadIdx.x;
  const size_t i = (size_t)row * 256 + tid;
  const float4 p0 = ((const float4*)P)[i];
  const float4 p1 = ((const float4*)P)[i + (size_t)NTOK * 256];
  const float4 rv = ((const float4*)res)[i];
  const float4 bv = ((const float4*)bias)[tid];
  float4 y;
  y.x = p0.x + p1.x + rv.x + bv.x;
  y.y = p0.y + p1.y + rv.y + bv.y;
  y.z = p0.z + p1.z + rv.z + bv.z;
  y.w = p0.w + p1.w + rv.w + bv.w;
  ((float4*)out)[i] = y;
}

// ---------------------------------------------------------------------------
// Merged Q + KV projection GEMM (round-9). Grid (32, 48).
// ---------------------------------------------------------------------------
__global__ __launch_bounds__(256, 2) void qkv_k(
    const short* __restrict__ Aq, const short* __restrict__ Bq,
    short* __restrict__ Qb,
    const short* __restrict__ Akv, const short* __restrict__ Bkv,
    short* __restrict__ Kgp, short* __restrict__ Vgp) {
  __shared__ short sA[2][128 * 64];
  __shared__ short sB[2][64 * 64];
  const int tid = threadIdx.x;
  const int lane = tid & 63;
  const int w = tid >> 6;
  const int r15 = lane & 15, g4 = lane >> 4;
  const bool isQ = blockIdx.y < 16;
  const short* __restrict__ A = isQ ? Aq : Akv;
  const short* __restrict__ Bt = isQ ? Bq : Bkv;
  const size_t row0 = (size_t)blockIdx.x * 128;
  const size_t col0 = (size_t)(isQ ? blockIdx.y : blockIdx.y - 16) * 64;
  const int K = 1024;

  f32x4 acc[2][4];
#pragma unroll
  for (int i = 0; i < 2; i++)
#pragma unroll
    for (int j = 0; j < 4; j++) acc[i][j] = (f32x4){0.f, 0.f, 0.f, 0.f};

  auto stage = [&](int buf, int kt) {
    const int k0 = kt << 6;
#pragma unroll
    for (int i = 0; i < 4; i++) {
      int flat = i * 256 + tid;
      int row = flat >> 3;
      int col = k0 + (((flat & 7) ^ (row & 7)) << 3);
      g2l16(A + (row0 + row) * (size_t)K + col, &sA[buf][(i * 256 + w * 64) * 8]);
    }
#pragma unroll
    for (int i = 0; i < 2; i++) {
      int flat = i * 256 + tid;
      int row = flat >> 3;
      int col = k0 + (((flat & 7) ^ (row & 7)) << 3);
      g2l16(Bt + (col0 + row) * (size_t)K + col, &sB[buf][(i * 256 + w * 64) * 8]);
    }
  };

  stage(0, 0);
  __syncthreads();

  const int nk = K >> 6;
  for (int kt = 0; kt < nk; ++kt) {
    const int cur = kt & 1;
    if (kt + 1 < nk) stage(cur ^ 1, kt + 1);
#pragma unroll
    for (int kk = 0; kk < 2; ++kk) {
      bf16x8 af[2], bfr[4];
#pragma unroll
      for (int mi = 0; mi < 2; mi++) {
        int rowA = w * 32 + mi * 16 + r15;
        af[mi] = *(const bf16x8*)(&sA[cur][rowA * 64 +
                                           (((kk * 4 + g4) ^ (rowA & 7)) << 3)]);
      }
#pragma unroll
      for (int ni = 0; ni < 4; ni++) {
        int rowB = ni * 16 + r15;
        bfr[ni] = *(const bf16x8*)(&sB[cur][rowB * 64 +
                                            (((kk * 4 + g4) ^ (rowB & 7)) << 3)]);
      }
#pragma unroll
      for (int mi = 0; mi < 2; mi++)
#pragma unroll
        for (int ni = 0; ni < 4; ni++)
          acc[mi][ni] = __builtin_amdgcn_mfma_f32_16x16x32_bf16(af[mi], bfr[ni],
                                                                acc[mi][ni], 0, 0, 0);
    }
    __syncthreads();
  }

#pragma unroll
  for (int mi = 0; mi < 2; mi++) {
    size_t row = row0 + w * 32 + mi * 16 + (g4 << 2);
#pragma unroll
    for (int ni = 0; ni < 4; ni++) {
      size_t col = col0 + ni * 16 + r15;
#pragma unroll
      for (int r = 0; r < 4; r++) {
        float v = acc[mi][ni][r];
        if (isQ) {
          Qb[(row + r) * 1024 + col] = f2bf(v);
        } else {
          int tt = (int)(row + r) >> 2;
          int bb = (int)(row + r) & 3;
          int cc = (int)col;
          if (cc < 1024) {
            int hh = cc >> 6, dd = cc & 63;
            size_t base = (size_t)(bb * 16 + hh) * 65536 + (size_t)tt * 64;
            Kgp[base + ((((dd >> 3) ^ (tt & 7)) << 3) | (dd & 7))] = f2bf(v * 0.125f);
          } else {
            int hh = (cc >> 6) - 16, dd = cc & 63;
            size_t base = (size_t)(bb * 16 + hh) * 65536 + (size_t)(tt >> 6) * 4096;
            Vgp[base + ((tt >> 3) & 7) * 512 + dd * 8 + (tt & 7)] = f2bf(v);
          }
        }
      }
    }
  }
}

// ---------------------------------------------------------------------------
// Flash attention v2 (round-5 structure). MODE 0: causal self-attn (qt remap
// balances per-CU work); MODE 1: cross-attn (first 896 keys only).
// ---------------------------------------------------------------------------
template <int MODE>
__global__ __launch_bounds__(256, 2) void attn_k2(const short* __restrict__ Qm,
                                                  const short* __restrict__ Kg,
                                                  const short* __restrict__ Vg,
                                                  short* __restrict__ Om) {
  __shared__ short Kl[2][4096];
  __shared__ short Vl[2][4096];
  __shared__ short Pl[4][2048];
  const int tid = threadIdx.x;
  const int lane = tid & 63;
  const int w = tid >> 6;
  const int r15 = lane & 15, g4 = lane >> 4;
  const int bh = blockIdx.x;  // b*16+h
  const int by = blockIdx.y;
  const int qt = (MODE == 0) ? ((by < 4) ? by : 11 - by) : by;
  const int b = bh >> 4, h = bh & 15;
  const int qbase = qt * 128 + w * 32;
  const int ktDiag = qbase >> 6;

  bf16x8 qf[2][2];
#pragma unroll
  for (int g = 0; g < 2; g++)
#pragma unroll
    for (int hf = 0; hf < 2; hf++) {
      int row = qbase + g * 16 + r15;
      qf[g][hf] = *(const bf16x8*)(Qm + ((size_t)(row * 4 + b)) * 1024 + h * 64 +
                                   hf * 32 + g4 * 8);
    }

  const size_t kvbase = (size_t)bh * 65536;
  const int nkt = (MODE == 0) ? (2 * qt + 2) : 14;

  f32x4 o[2][4];
#pragma unroll
  for (int g = 0; g < 2; g++)
#pragma unroll
    for (int ni = 0; ni < 4; ni++) o[g][ni] = (f32x4){0.f, 0.f, 0.f, 0.f};
  float mrun[2][4], lrun[2][4];
#pragma unroll
  for (int g = 0; g < 2; g++)
#pragma unroll
    for (int r = 0; r < 4; r++) { mrun[g][r] = -1e30f; lrun[g][r] = 0.f; }

  {
    const size_t tb = kvbase;
#pragma unroll
    for (int i = 0; i < 2; i++) {
      g2l16(Kg + tb + (size_t)(i * 256 + tid) * 8, &Kl[0][(i * 256 + w * 64) * 8]);
      g2l16(Vg + tb + (size_t)(i * 256 + tid) * 8, &Vl[0][(i * 256 + w * 64) * 8]);
    }
  }
  __syncthreads();

  for (int kt = 0; kt < nkt; kt++) {
    const int cur = kt & 1;
    if (kt + 1 < nkt) {
      const size_t tb = kvbase + (size_t)(kt + 1) * 4096;
#pragma unroll
      for (int i = 0; i < 2; i++) {
        g2l16(Kg + tb + (size_t)(i * 256 + tid) * 8,
              &Kl[cur ^ 1][(i * 256 + w * 64) * 8]);
        g2l16(Vg + tb + (size_t)(i * 256 + tid) * 8,
              &Vl[cur ^ 1][(i * 256 + w * 64) * 8]);
      }
    }

    const bool active = (MODE == 1) || (kt * 64 <= qbase + 31);
    if (active) {
      bf16x8 kb[4][2];
#pragma unroll
      for (int ni = 0; ni < 4; ni++) {
        int row = ni * 16 + r15;
        kb[ni][0] = *(const bf16x8*)(&Kl[cur][row * 64 + ((g4 ^ (row & 7)) << 3)]);
        kb[ni][1] =
            *(const bf16x8*)(&Kl[cur][row * 64 + (((g4 + 4) ^ (row & 7)) << 3)]);
      }
      f32x4 sf[2][4];
#pragma unroll
      for (int g = 0; g < 2; g++)
#pragma unroll
        for (int ni = 0; ni < 4; ni++) {
          f32x4 s = (f32x4){0.f, 0.f, 0.f, 0.f};
          s = __builtin_amdgcn_mfma_f32_16x16x32_bf16(qf[g][0], kb[ni][0], s, 0, 0, 0);
          s = __builtin_amdgcn_mfma_f32_16x16x32_bf16(qf[g][1], kb[ni][1], s, 0, 0, 0);
          sf[g][ni] = s;
        }
      if (MODE == 0 && kt >= ktDiag) {
#pragma unroll
        for (int g = 0; g < 2; g++)
#pragma unroll
          for (int ni = 0; ni < 4; ni++)
#pragma unroll
            for (int r = 0; r < 4; r++) {
              int q = qbase + g * 16 + g4 * 4 + r;
              int key = kt * 64 + ni * 16 + r15;
              if (key > q) sf[g][ni][r] = -1e30f;
            }
      }
#pragma unroll
      for (int g = 0; g < 2; g++) {
        float corr[4];
#pragma unroll
        for (int r = 0; r < 4; r++) {
          float m = fmaxf(fmaxf(sf[g][0][r], sf[g][1][r]),
                          fmaxf(sf[g][2][r], sf[g][3][r]));
          m = fmaxf(m, __shfl_xor(m, 1));
          m = fmaxf(m, __shfl_xor(m, 2));
          m = fmaxf(m, __shfl_xor(m, 4));
          m = fmaxf(m, __shfl_xor(m, 8));
          float mn = fmaxf(mrun[g][r], m);
          corr[r] = __expf(mrun[g][r] - mn);
          mrun[g][r] = mn;
        }
        float rs[4] = {0.f, 0.f, 0.f, 0.f};
#pragma unroll
        for (int ni = 0; ni < 4; ni++)
#pragma unroll
          for (int r = 0; r < 4; r++) {
            float p = __expf(sf[g][ni][r] - mrun[g][r]);
            sf[g][ni][r] = p;
            rs[r] += p;
          }
#pragma unroll
        for (int r = 0; r < 4; r++) {
          rs[r] += __shfl_xor(rs[r], 1);
          rs[r] += __shfl_xor(rs[r], 2);
          rs[r] += __shfl_xor(rs[r], 4);
          rs[r] += __shfl_xor(rs[r], 8);
          lrun[g][r] = lrun[g][r] * corr[r] + rs[r];
        }
#pragma unroll
        for (int ni = 0; ni < 4; ni++)
#pragma unroll
          for (int r = 0; r < 4; r++) o[g][ni][r] *= corr[r];
#pragma unroll
        for (int ni = 0; ni < 4; ni++)
#pragma unroll
          for (int r = 0; r < 4; r++) {
            int qr = g * 16 + g4 * 4 + r;
            int key = ni * 16 + r15;
            Pl[w][qr * 64 + ((((key >> 3) ^ ((qr >> 1) & 7)) << 3) | (key & 7))] =
                f2bf(sf[g][ni][r]);
          }
      }
#pragma unroll
      for (int kk = 0; kk < 2; kk++) {
        int gw = kk * 4 + g4;
        bf16x8 pa0 = *(const bf16x8*)(&Pl[w][r15 * 64 + ((gw ^ ((r15 >> 1) & 7)) << 3)]);
        bf16x8 pa1 =
            *(const bf16x8*)(&Pl[w][(16 + r15) * 64 + ((gw ^ ((r15 >> 1) & 7)) << 3)]);
#pragma unroll
        for (int ni = 0; ni < 4; ni++) {
          bf16x8 vb = *(const bf16x8*)(&Vl[cur][(gw * 64 + ni * 16 + r15) * 8]);
          o[0][ni] = __builtin_amdgcn_mfma_f32_16x16x32_bf16(pa0, vb, o[0][ni], 0, 0, 0);
          o[1][ni] = __builtin_amdgcn_mfma_f32_16x16x32_bf16(pa1, vb, o[1][ni], 0, 0, 0);
        }
      }
    }
    __syncthreads();
  }

#pragma unroll
  for (int g = 0; g < 2; g++) {
    float inv[4];
#pragma unroll
    for (int r = 0; r < 4; r++) inv[r] = 1.f / lrun[g][r];
#pragma unroll
    for (int ni = 0; ni < 4; ni++) {
      int col = h * 64 + ni * 16 + r15;
#pragma unroll
      for (int r = 0; r < 4; r++) {
        int tg = qbase + g * 16 + g4 * 4 + r;
        Om[((size_t)(tg * 4 + b)) * 1024 + col] = f2bf(o[g][ni][r] * inv[r]);
      }
    }
  }
}

// ---------------------------------------------------------------------------
// LayerNorm over D=1024; optional fp32 out, bf16 normed out, bf16 raw-x out.
// ---------------------------------------------------------------------------
__global__ __launch_bounds__(256) void ln_k(const float* __restrict__ x,
                                            const float* __restrict__ gw,
                                            const float* __restrict__ bw,
                                            float* __restrict__ outF,
                                            short* __restrict__ outB,
                                            short* __restrict__ outXB) {
  const int row = blockIdx.x, tid = threadIdx.x;
  const float4 v = ((const float4*)(x + (size_t)row * 1024))[tid];
  float s = v.x + v.y + v.z + v.w;
  float ss = v.x * v.x + v.y * v.y + v.z * v.z + v.w * v.w;
#pragma unroll
  for (int d = 32; d >= 1; d >>= 1) {
    s += __shfl_xor(s, d);
    ss += __shfl_xor(ss, d);
  }
  __shared__ float red[8];
  const int w = tid >> 6;
  if ((tid & 63) == 0) { red[w] = s; red[4 + w] = ss; }
  __syncthreads();
  s = red[0] + red[1] + red[2] + red[3];
  ss = red[4] + red[5] + red[6] + red[7];
  const float mean = s * (1.f / 1024.f);
  const float var = ss * (1.f / 1024.f) - mean * mean;
  const float rstd = rsqrtf(var + 1e-5f);
  const float4 gv = ((const float4*)gw)[tid];
  const float4 bv = ((const float4*)bw)[tid];
  float4 y;
  y.x = (v.x - mean) * rstd * gv.x + bv.x;
  y.y = (v.y - mean) * rstd * gv.y + bv.y;
  y.z = (v.z - mean) * rstd * gv.z + bv.z;
  y.w = (v.w - mean) * rstd * gv.w + bv.w;
  if (outF) ((float4*)(outF + (size_t)row * 1024))[tid] = y;
  if (outB) {
    short4 ob;
    ob.x = f2bf(y.x); ob.y = f2bf(y.y); ob.z = f2bf(y.z); ob.w = f2bf(y.w);
    ((short4*)(outB + (size_t)row * 1024))[tid] = ob;
  }
  if (outXB) {
    short4 ob;
    ob.x = f2bf(v.x); ob.y = f2bf(v.y); ob.z = f2bf(v.z); ob.w = f2bf(v.w);
    ((short4*)(outXB + (size_t)row * 1024))[tid] = ob;
  }
}

// ---------------------------------------------------------------------------
// Fused prep: all 8 weight transposes (fp32 [K][N] -> bf16 [N][K]) plus the
// enc_out fp32->bf16 cast, in ONE launch (8192 blocks).
// ---------------------------------------------------------------------------
__global__ __launch_bounds__(256) void prep_k(
    const float* __restrict__ Wq1, const float* __restrict__ Wkv1,
    const float* __restrict__ Wo1, const float* __restrict__ Wq2,
    const float* __restrict__ Wkv2, const float* __restrict__ Wo2,
    const float* __restrict__ Wff1, const float* __restrict__ Wff2,
    const float* __restrict__ enc,
    short* __restrict__ q1t, short* __restrict__ kv1t, short* __restrict__ o1t,
    short* __restrict__ q2t, short* __restrict__ kv2t, short* __restrict__ o2t,
    short* __restrict__ ff1t, short* __restrict__ ff2t, short* __restrict__ ebf) {
  const int id = blockIdx.x;
  const int tid = threadIdx.x;
  if (id >= 4096) {
    const size_t i = (size_t)(id - 4096) * 256 + tid;
    const float4 v = ((const float4*)enc)[i];
    short4 ob;
    ob.x = f2bf(v.x); ob.y = f2bf(v.y); ob.z = f2bf(v.z); ob.w = f2bf(v.w);
    ((short4*)ebf)[i] = ob;
    return;
  }
  const float* in;
  short* out;
  int K, N, base;
  if (id < 256)       { in = Wq1;  out = q1t;  K = 1024; N = 1024; base = 0; }
  else if (id < 768)  { in = Wkv1; out = kv1t; K = 1024; N = 2048; base = 256; }
  else if (id < 1024) { in = Wo1;  out = o1t;  K = 1024; N = 1024; base = 768; }
  else if (id < 1280) { in = Wq2;  out = q2t;  K = 1024; N = 1024; base = 1024; }
  else if (id < 1792) { in = Wkv2; out = kv2t; K = 1024; N = 2048; base = 1280; }
  else if (id < 2048) { in = Wo2;  out = o2t;  K = 1024; N = 1024; base = 1792; }
  else if (id < 3072) { in = Wff1; out = ff1t; K = 1024; N = 4096; base = 2048; }
  else                { in = Wff2; out = ff2t; K = 4096; N = 1024; base = 3072; }
  const int lid = id - base;
  const int nkb = K >> 6;
  const int k0 = (lid % nkb) * 64;
  const int n0 = (lid / nkb) * 64;

  __shared__ float t[64][65];
#pragma unroll
  for (int i = 0; i < 16; i++) {
    int flat = i * 256 + tid;
    int r = flat >> 6, c = flat & 63;
    t[r][c] = in[(size_t)(k0 + r) * N + n0 + c];
  }
  __syncthreads();
#pragma unroll
  for (int i = 0; i < 16; i++) {
    int flat = i * 256 + tid;
    int r = flat >> 6, c = flat & 63;
    out[(size_t)(n0 + r) * K + k0 + c] = f2bf(t[c][r]);
  }
}

extern "C" void kernel_launch(void* const* d_in, const int* in_sizes, int n_in,
                              void* d_out, int out_size, void* d_ws, size_t ws_size,
                              hipStream_t stream) {
  const float* dec_inp = (const float*)d_in[0];
  const float* enc_out = (const float*)d_in[1];
  const float* W_q1 = (const float*)d_in[4];
  const float* W_kv1 = (const float*)d_in[5];
  const float* W_o1 = (const float*)d_in[6];
  const float* g1 = (const float*)d_in[7];
  const float* b1 = (const float*)d_in[8];
  const float* W_q2 = (const float*)d_in[9];
  const float* W_kv2 = (const float*)d_in[10];
  const float* W_o2 = (const float*)d_in[11];
  const float* g2 = (const float*)d_in[12];
  const float* b2 = (const float*)d_in[13];
  const float* W_ff1 = (const float*)d_in[14];
  const float* b_ff1 = (const float*)d_in[15];
  const float* W_ff2 = (const float*)d_in[16];
  const float* b_ff2 = (const float*)d_in[17];
  const float* g3 = (const float*)d_in[18];
  const float* b3 = (const float*)d_in[19];
  float* out = (float*)d_out;

  char* ws = (char*)d_ws;
  size_t off = 0;
  auto alloc = [&](size_t bytes) -> void* {
    void* p = ws + off;
    off += (bytes + 255) & ~(size_t)255;
    return p;
  };
  short* Wq1t = (short*)alloc(1024ull * 1024 * 2);
  short* Wkv1t = (short*)alloc(2048ull * 1024 * 2);
  short* Wo1t = (short*)alloc(1024ull * 1024 * 2);
  short* Wq2t = (short*)alloc(1024ull * 1024 * 2);
  short* Wkv2t = (short*)alloc(2048ull * 1024 * 2);
  short* Wo2t = (short*)alloc(1024ull * 1024 * 2);
  short* Wff1t = (short*)alloc(4096ull * 1024 * 2);
  short* Wff2t = (short*)alloc(1024ull * 4096 * 2);
  short* Xbf = (short*)alloc((size_t)NTOK * 1024 * 2);
  short* Ebf = (short*)alloc((size_t)NTOK * 1024 * 2);
  short* Cbf = (short*)alloc((size_t)NTOK * 1024 * 2);
  short* Qb = (short*)alloc((size_t)NTOK * 1024 * 2);   // \  reused as the
  short* Kg = (short*)alloc(64ull * 65536 * 2);          //  } 32MB fp32 split-K
  short* Vg = (short*)alloc(64ull * 65536 * 2);          //  } partial planes
  short* VECb = (short*)alloc((size_t)NTOK * 1024 * 2); // /  for FFN2
  float* OUT1 = (float*)alloc((size_t)NTOK * 1024 * 4);
  float* H2f = (float*)alloc((size_t)NTOK * 1024 * 4);
  float* OUT2 = (float*)alloc((size_t)NTOK * 1024 * 4);
  short* FF1 = (short*)alloc((size_t)NTOK * 4096 * 2);
  short* H2b = Xbf;  // Xbf dead after qkv1
  short* H3b = Cbf;  // Cbf dead after qkv1
  float* PartF = (float*)Qb;  // Qb..VECb = 32MB contiguous, dead after o2

  dim3 blk(256, 1, 1);

  // all weight transposes + enc cast in one launch
  prep_k<<<8192, blk, 0, stream>>>(W_q1, W_kv1, W_o1, W_q2, W_kv2, W_o2, W_ff1,
                                   W_ff2, enc_out, Wq1t, Wkv1t, Wo1t, Wq2t,
                                   Wkv2t, Wo2t, Wff1t, Wff2t, Ebf);
  // LN(dec_inp) -> Cbf (bf16) and raw dec_inp -> Xbf (bf16) in one pass
  ln_k<<<4096, blk, 0, stream>>>(dec_inp, g1, b1, nullptr, Cbf, Xbf);

  // ---- self attention ----
  qkv_k<<<dim3(32, 48), blk, 0, stream>>>(Xbf, Wq1t, Qb, Cbf, Wkv1t, Kg, Vg);
  attn_k2<0><<<dim3(64, 8), blk, 0, stream>>>(Qb, Kg, Vg, VECb);
  gemm_bt<1, 64><<<dim3(32, 16), blk, 0, stream>>>(
      VECb, Wo1t, OUT1, nullptr, dec_inp, nullptr, 4096, 1024, 1024, 1024);
  // ---- cross attention ----
  ln_k<<<4096, blk, 0, stream>>>(OUT1, g2, b2, H2f, H2b, nullptr);
  qkv_k<<<dim3(32, 48), blk, 0, stream>>>(H2b, Wq2t, Qb, Ebf, Wkv2t, Kg, Vg);
  attn_k2<1><<<dim3(64, 8), blk, 0, stream>>>(Qb, Kg, Vg, VECb);
  gemm_bt<1, 64><<<dim3(32, 16), blk, 0, stream>>>(
      VECb, Wo2t, OUT2, nullptr, H2f, nullptr, 4096, 1024, 1024, 1024);
  // ---- FFN ----
  ln_k<<<4096, blk, 0, stream>>>(OUT2, g3, b3, nullptr, H3b, nullptr);
  gemm8p<2><<<dim3(16, 16), dim3(512, 1, 1), 0, stream>>>(
      H3b, Wff1t, nullptr, FF1, nullptr, b_ff1, 4096, 4096, 1024);
  // FFN2 split-K=2: grid (32,16,2) = 1024 blocks -> 3 blocks/CU
  gemm_bt<5, 64><<<dim3(32, 16, 2), blk, 0, stream>>>(
      FF1, Wff2t, PartF, nullptr, nullptr, nullptr, 4096, 1024, 4096, 2048);
  ffn2_fin<<<4096, blk, 0, stream>>>(PartF, OUT2, b_ff2, out);
}

// Round 14
// 350.714 us; speedup vs baseline: 1.0396x; 1.0396x over previous
//
#include <hip/hip_runtime.h>
#include <hip/hip_bf16.h>

// Sizes (fixed by the problem)
#define T_ 1024
#define S_ 1024
#define B_ 4
#define D_ 1024
#define H_ 16
#define DH_ 64
#define DI_ 4096
#define NTOK 4096          // T*B

typedef __attribute__((ext_vector_type(8))) short bf16x8;
typedef __attribute__((ext_vector_type(4))) float f32x4;

__device__ __forceinline__ short f2bf(float f) {
  unsigned u = __builtin_bit_cast(unsigned, f);
  u += 0x7fffu + ((u >> 16) & 1u);
  return (short)(u >> 16);
}

__device__ __forceinline__ void g2l16(const void* g, void* l) {
  __builtin_amdgcn_global_load_lds(
      (const __attribute__((address_space(1))) unsigned int*)g,
      (__attribute__((address_space(3))) unsigned int*)l, 16, 0, 0);
}

__device__ __forceinline__ void bar() {
  asm volatile("" ::: "memory");
  __builtin_amdgcn_s_barrier();
  asm volatile("" ::: "memory");
}

// ---------------------------------------------------------------------------
// 8-phase 256x256 GEMM (T2+T3+T4+T5) for FFN1 (grid 16x16 = 256 blocks).
// bv0 (nh0 B-frags) stays live ph0->ph3 (round-12: LDS reads 28KB -> 24KB).
// ---------------------------------------------------------------------------
template <int EPI>
__global__ __launch_bounds__(512, 2) void gemm8p(
    const short* __restrict__ A, const short* __restrict__ Bt,
    float* __restrict__ outF, short* __restrict__ outB,
    const float* __restrict__ res, const float* __restrict__ bias,
    int M, int N, int K) {
  __shared__ short sA[2][256 * 64];
  __shared__ short sB[2][256 * 64];
  const int tid = threadIdx.x;
  const int lane = tid & 63;
  const int w = tid >> 6;            // 0..7
  const int wm = w >> 2, wn = w & 3; // 2M x 4N wave grid
  const int r15 = lane & 15, g4 = lane >> 4;
  const size_t row0 = (size_t)blockIdx.x * 256;
  const size_t col0 = (size_t)blockIdx.y * 256;

  f32x4 acc[8][4];
#pragma unroll
  for (int i = 0; i < 8; i++)
#pragma unroll
    for (int j = 0; j < 4; j++) acc[i][j] = (f32x4){0.f, 0.f, 0.f, 0.f};

  auto stageA = [&](int buf, int s, int kt) {
    const int k0 = kt << 6;
#pragma unroll
    for (int j = 0; j < 2; ++j) {
      const int c = j * 8 + w;
      const int rb = ((c >> 3) << 7) + (s << 6) + ((c & 7) << 3);
      const int row = rb + (lane >> 3);
      const int col = k0 + (((lane & 7) ^ (row & 7)) << 3);
      g2l16(A + (row0 + row) * (size_t)K + col, &sA[buf][rb * 64]);
    }
  };
  auto stageB = [&](int buf, int s, int kt) {
    const int k0 = kt << 6;
#pragma unroll
    for (int j = 0; j < 2; ++j) {
      const int c = j * 8 + w;
      const int rb = ((c >> 2) << 6) + (s << 5) + ((c & 3) << 3);
      const int row = rb + (lane >> 3);
      const int col = k0 + (((lane & 7) ^ (row & 7)) << 3);
      g2l16(Bt + (col0 + row) * (size_t)K + col, &sB[buf][rb * 64]);
    }
  };

  const int nk = K >> 6;
  stageA(0, 0, 0); stageA(0, 1, 0); stageB(0, 0, 0); stageB(0, 1, 0);
  if (nk > 1) {
    stageA(1, 0, 1); stageB(1, 1, 1);
    asm volatile("s_waitcnt vmcnt(4)" ::: "memory");
  } else {
    asm volatile("s_waitcnt vmcnt(0)" ::: "memory");
  }
  bar();

  bf16x8 af[4][2], bv0[2][2], bv1[2][2];
  for (int t = 0; t < nk; ++t) {
    const int cur = t & 1;
    const short* cA = sA[cur];
    const short* cB = sB[cur];
    // phase 0: (mh0, nh0); stage A-S1(t+1)
#pragma unroll
    for (int mi = 0; mi < 4; mi++) {
      const int rowA = wm * 128 + mi * 16 + r15;
#pragma unroll
      for (int kk = 0; kk < 2; kk++)
        af[mi][kk] = *(const bf16x8*)(cA + rowA * 64 +
                                      (((kk * 4 + g4) ^ (rowA & 7)) << 3));
    }
#pragma unroll
    for (int ni = 0; ni < 2; ni++) {
      const int rowB = wn * 64 + ni * 16 + r15;
#pragma unroll
      for (int kk = 0; kk < 2; kk++)
        bv0[ni][kk] = *(const bf16x8*)(cB + rowB * 64 +
                                       (((kk * 4 + g4) ^ (rowB & 7)) << 3));
    }
    if (t + 1 < nk) stageA(cur ^ 1, 1, t + 1);
    bar();
    asm volatile("s_waitcnt lgkmcnt(0)" ::: "memory");
    __builtin_amdgcn_s_setprio(1);
#pragma unroll
    for (int kk = 0; kk < 2; kk++)
#pragma unroll
      for (int mi = 0; mi < 4; mi++)
#pragma unroll
        for (int ni = 0; ni < 2; ni++)
          acc[mi][ni] = __builtin_amdgcn_mfma_f32_16x16x32_bf16(
              af[mi][kk], bv0[ni][kk], acc[mi][ni], 0, 0, 0);
    __builtin_amdgcn_s_setprio(0);
    bar();
    // phase 1: (mh0, nh1), af reused; stage B-S0(t+1)
#pragma unroll
    for (int ni = 0; ni < 2; ni++) {
      const int rowB = wn * 64 + (2 + ni) * 16 + r15;
#pragma unroll
      for (int kk = 0; kk < 2; kk++)
        bv1[ni][kk] = *(const bf16x8*)(cB + rowB * 64 +
                                       (((kk * 4 + g4) ^ (rowB & 7)) << 3));
    }
    if (t + 1 < nk) stageB(cur ^ 1, 0, t + 1);
    bar();
    asm volatile("s_waitcnt lgkmcnt(0)" ::: "memory");
    __builtin_amdgcn_s_setprio(1);
#pragma unroll
    for (int kk = 0; kk < 2; kk++)
#pragma unroll
      for (int mi = 0; mi < 4; mi++)
#pragma unroll
        for (int ni = 0; ni < 2; ni++)
          acc[mi][2 + ni] = __builtin_amdgcn_mfma_f32_16x16x32_bf16(
              af[mi][kk], bv1[ni][kk], acc[mi][2 + ni], 0, 0, 0);
    __builtin_amdgcn_s_setprio(0);
    bar();
    // phase 2: (mh1, nh1), bv1 reused; stage A-S0(t+2)
#pragma unroll
    for (int mi = 0; mi < 4; mi++) {
      const int rowA = wm * 128 + (4 + mi) * 16 + r15;
#pragma unroll
      for (int kk = 0; kk < 2; kk++)
        af[mi][kk] = *(const bf16x8*)(cA + rowA * 64 +
                                      (((kk * 4 + g4) ^ (rowA & 7)) << 3));
    }
    if (t + 2 < nk) stageA(cur, 0, t + 2);
    bar();
    asm volatile("s_waitcnt lgkmcnt(0)" ::: "memory");
    __builtin_amdgcn_s_setprio(1);
#pragma unroll
    for (int kk = 0; kk < 2; kk++)
#pragma unroll
      for (int mi = 0; mi < 4; mi++)
#pragma unroll
        for (int ni = 0; ni < 2; ni++)
          acc[4 + mi][2 + ni] = __builtin_amdgcn_mfma_f32_16x16x32_bf16(
              af[mi][kk], bv1[ni][kk], acc[4 + mi][2 + ni], 0, 0, 0);
    __builtin_amdgcn_s_setprio(0);
    bar();
    // phase 3: (mh1, nh0), af + bv0 reused; stage B-S1(t+2)
    if (t + 2 < nk) stageB(cur, 1, t + 2);
    bar();
    asm volatile("s_waitcnt lgkmcnt(0)" ::: "memory");
    __builtin_amdgcn_s_setprio(1);
#pragma unroll
    for (int kk = 0; kk < 2; kk++)
#pragma unroll
      for (int mi = 0; mi < 4; mi++)
#pragma unroll
        for (int ni = 0; ni < 2; ni++)
          acc[4 + mi][ni] = __builtin_amdgcn_mfma_f32_16x16x32_bf16(
              af[mi][kk], bv0[ni][kk], acc[4 + mi][ni], 0, 0, 0);
    __builtin_amdgcn_s_setprio(0);
    if (t + 2 < nk)
      asm volatile("s_waitcnt vmcnt(4)" ::: "memory");
    else if (t + 1 < nk)
      asm volatile("s_waitcnt vmcnt(0)" ::: "memory");
    bar();
  }

#pragma unroll
  for (int mi = 0; mi < 8; mi++) {
    size_t row = row0 + wm * 128 + mi * 16 + (g4 << 2);
#pragma unroll
    for (int ni = 0; ni < 4; ni++) {
      size_t col = col0 + wn * 64 + ni * 16 + r15;
      float bcol = (EPI == 2 || EPI == 3) ? bias[col] : 0.f;
#pragma unroll
      for (int r = 0; r < 4; r++) {
        size_t idx = (row + r) * (size_t)N + col;
        float v = acc[mi][ni][r];
        if (EPI == 0) {
          outB[idx] = f2bf(v);
        } else if (EPI == 1) {
          outF[idx] = v + res[idx];
        } else if (EPI == 2) {
          float x = v + bcol;
          float gl = 0.5f * x * (1.f + erff(x * 0.70710678118654752f));
          outB[idx] = f2bf(gl);
        } else {
          outF[idx] = v + bcol + res[idx];
        }
      }
    }
  }
}

// ---------------------------------------------------------------------------
// 2-phase GEMM (round-5/9 structure, best measured for the thin shapes):
// stage(t+1) before compute(t), one __syncthreads per K-step.
// BN=64: LDS 48KB; grid 512 -> 2 blocks/CU (the measured-best config).
// EPI 1: outF = acc + res; EPI 3: outF = acc + bias + res.
// ---------------------------------------------------------------------------
template <int EPI, int BN>
__global__ __launch_bounds__(256, 2) void gemm_bt(
    const short* __restrict__ A, const short* __restrict__ Bt,
    float* __restrict__ outF, short* __restrict__ outB,
    const float* __restrict__ res, const float* __restrict__ bias,
    int M, int N, int K) {
  constexpr int WCOLS = BN / 64;
  constexpr int MI = (WCOLS == 2) ? 4 : 2;
  constexpr int BLOADS = BN / 32;
  __shared__ short sA[2][128 * 64];
  __shared__ short sB[2][BN * 64];
  const int tid = threadIdx.x;
  const int lane = tid & 63;
  const int w = tid >> 6;
  const int wr = (WCOLS == 2) ? (w >> 1) : w;
  const int wc = (WCOLS == 2) ? (w & 1) : 0;
  const int r15 = lane & 15, g4 = lane >> 4;
  const size_t row0 = (size_t)blockIdx.x * 128;
  const size_t col0 = (size_t)blockIdx.y * BN;

  f32x4 acc[MI][4];
#pragma unroll
  for (int i = 0; i < MI; i++)
#pragma unroll
    for (int j = 0; j < 4; j++) acc[i][j] = (f32x4){0.f, 0.f, 0.f, 0.f};

  auto stage = [&](int buf, int kt) {
    const int k0 = kt << 6;
#pragma unroll
    for (int i = 0; i < 4; i++) {
      int flat = i * 256 + tid;
      int row = flat >> 3;
      int col = k0 + (((flat & 7) ^ (row & 7)) << 3);
      g2l16(A + (row0 + row) * (size_t)K + col, &sA[buf][(i * 256 + w * 64) * 8]);
    }
#pragma unroll
    for (int i = 0; i < BLOADS; i++) {
      int flat = i * 256 + tid;
      int row = flat >> 3;
      int col = k0 + (((flat & 7) ^ (row & 7)) << 3);
      g2l16(Bt + (col0 + row) * (size_t)K + col, &sB[buf][(i * 256 + w * 64) * 8]);
    }
  };

  stage(0, 0);
  __syncthreads();

  const int nk = K >> 6;
  for (int kt = 0; kt < nk; ++kt) {
    const int cur = kt & 1;
    if (kt + 1 < nk) stage(cur ^ 1, kt + 1);
#pragma unroll
    for (int kk = 0; kk < 2; ++kk) {
      bf16x8 af[MI], bfr[4];
#pragma unroll
      for (int mi = 0; mi < MI; mi++) {
        int rowA = wr * (MI * 16) + mi * 16 + r15;
        af[mi] = *(const bf16x8*)(&sA[cur][rowA * 64 +
                                           (((kk * 4 + g4) ^ (rowA & 7)) << 3)]);
      }
#pragma unroll
      for (int ni = 0; ni < 4; ni++) {
        int rowB = wc * 64 + ni * 16 + r15;
        bfr[ni] = *(const bf16x8*)(&sB[cur][rowB * 64 +
                                            (((kk * 4 + g4) ^ (rowB & 7)) << 3)]);
      }
#pragma unroll
      for (int mi = 0; mi < MI; mi++)
#pragma unroll
        for (int ni = 0; ni < 4; ni++)
          acc[mi][ni] = __builtin_amdgcn_mfma_f32_16x16x32_bf16(af[mi], bfr[ni],
                                                                acc[mi][ni], 0, 0, 0);
    }
    __syncthreads();
  }

#pragma unroll
  for (int mi = 0; mi < MI; mi++) {
    size_t row = row0 + wr * (MI * 16) + mi * 16 + (g4 << 2);
#pragma unroll
    for (int ni = 0; ni < 4; ni++) {
      size_t col = col0 + wc * 64 + ni * 16 + r15;
      float bcol = (EPI == 2 || EPI == 3) ? bias[col] : 0.f;
#pragma unroll
      for (int r = 0; r < 4; r++) {
        size_t idx = (row + r) * (size_t)N + col;
        float v = acc[mi][ni][r];
        if (EPI == 0) {
          outB[idx] = f2bf(v);
        } else if (EPI == 1) {
          outF[idx] = v + res[idx];
        } else if (EPI == 2) {
          float x = v + bcol;
          float gl = 0.5f * x * (1.f + erff(x * 0.70710678118654752f));
          outB[idx] = f2bf(gl);
        } else {
          outF[idx] = v + bcol + res[idx];
        }
      }
    }
  }
}

// ---------------------------------------------------------------------------
// Merged Q + KV projection GEMM (round-9). Grid (32, 48).
// ---------------------------------------------------------------------------
__global__ __launch_bounds__(256, 2) void qkv_k(
    const short* __restrict__ Aq, const short* __restrict__ Bq,
    short* __restrict__ Qb,
    const short* __restrict__ Akv, const short* __restrict__ Bkv,
    short* __restrict__ Kgp, short* __restrict__ Vgp) {
  __shared__ short sA[2][128 * 64];
  __shared__ short sB[2][64 * 64];
  const int tid = threadIdx.x;
  const int lane = tid & 63;
  const int w = tid >> 6;
  const int r15 = lane & 15, g4 = lane >> 4;
  const bool isQ = blockIdx.y < 16;
  const short* __restrict__ A = isQ ? Aq : Akv;
  const short* __restrict__ Bt = isQ ? Bq : Bkv;
  const size_t row0 = (size_t)blockIdx.x * 128;
  const size_t col0 = (size_t)(isQ ? blockIdx.y : blockIdx.y - 16) * 64;
  const int K = 1024;

  f32x4 acc[2][4];
#pragma unroll
  for (int i = 0; i < 2; i++)
#pragma unroll
    for (int j = 0; j < 4; j++) acc[i][j] = (f32x4){0.f, 0.f, 0.f, 0.f};

  auto stage = [&](int buf, int kt) {
    const int k0 = kt << 6;
#pragma unroll
    for (int i = 0; i < 4; i++) {
      int flat = i * 256 + tid;
      int row = flat >> 3;
      int col = k0 + (((flat & 7) ^ (row & 7)) << 3);
      g2l16(A + (row0 + row) * (size_t)K + col, &sA[buf][(i * 256 + w * 64) * 8]);
    }
#pragma unroll
    for (int i = 0; i < 2; i++) {
      int flat = i * 256 + tid;
      int row = flat >> 3;
      int col = k0 + (((flat & 7) ^ (row & 7)) << 3);
      g2l16(Bt + (col0 + row) * (size_t)K + col, &sB[buf][(i * 256 + w * 64) * 8]);
    }
  };

  stage(0, 0);
  __syncthreads();

  const int nk = K >> 6;
  for (int kt = 0; kt < nk; ++kt) {
    const int cur = kt & 1;
    if (kt + 1 < nk) stage(cur ^ 1, kt + 1);
#pragma unroll
    for (int kk = 0; kk < 2; ++kk) {
      bf16x8 af[2], bfr[4];
#pragma unroll
      for (int mi = 0; mi < 2; mi++) {
        int rowA = w * 32 + mi * 16 + r15;
        af[mi] = *(const bf16x8*)(&sA[cur][rowA * 64 +
                                           (((kk * 4 + g4) ^ (rowA & 7)) << 3)]);
      }
#pragma unroll
      for (int ni = 0; ni < 4; ni++) {
        int rowB = ni * 16 + r15;
        bfr[ni] = *(const bf16x8*)(&sB[cur][rowB * 64 +
                                            (((kk * 4 + g4) ^ (rowB & 7)) << 3)]);
      }
#pragma unroll
      for (int mi = 0; mi < 2; mi++)
#pragma unroll
        for (int ni = 0; ni < 4; ni++)
          acc[mi][ni] = __builtin_amdgcn_mfma_f32_16x16x32_bf16(af[mi], bfr[ni],
                                                                acc[mi][ni], 0, 0, 0);
    }
    __syncthreads();
  }

#pragma unroll
  for (int mi = 0; mi < 2; mi++) {
    size_t row = row0 + w * 32 + mi * 16 + (g4 << 2);
#pragma unroll
    for (int ni = 0; ni < 4; ni++) {
      size_t col = col0 + ni * 16 + r15;
#pragma unroll
      for (int r = 0; r < 4; r++) {
        float v = acc[mi][ni][r];
        if (isQ) {
          Qb[(row + r) * 1024 + col] = f2bf(v);
        } else {
          int tt = (int)(row + r) >> 2;
          int bb = (int)(row + r) & 3;
          int cc = (int)col;
          if (cc < 1024) {
            int hh = cc >> 6, dd = cc & 63;
            size_t base = (size_t)(bb * 16 + hh) * 65536 + (size_t)tt * 64;
            Kgp[base + ((((dd >> 3) ^ (tt & 7)) << 3) | (dd & 7))] = f2bf(v * 0.125f);
          } else {
            int hh = (cc >> 6) - 16, dd = cc & 63;
            size_t base = (size_t)(bb * 16 + hh) * 65536 + (size_t)(tt >> 6) * 4096;
            Vgp[base + ((tt >> 3) & 7) * 512 + dd * 8 + (tt & 7)] = f2bf(v);
          }
        }
      }
    }
  }
}

// ---------------------------------------------------------------------------
// Flash attention v2 (round-5 structure). MODE 0: causal self-attn (qt remap
// balances per-CU work); MODE 1: cross-attn (first 896 keys only).
// ---------------------------------------------------------------------------
template <int MODE>
__global__ __launch_bounds__(256, 2) void attn_k2(const short* __restrict__ Qm,
                                                  const short* __restrict__ Kg,
                                                  const short* __restrict__ Vg,
                                                  short* __restrict__ Om) {
  __shared__ short Kl[2][4096];
  __shared__ short Vl[2][4096];
  __shared__ short Pl[4][2048];
  const int tid = threadIdx.x;
  const int lane = tid & 63;
  const int w = tid >> 6;
  const int r15 = lane & 15, g4 = lane >> 4;
  const int bh = blockIdx.x;  // b*16+h
  const int by = blockIdx.y;
  const int qt = (MODE == 0) ? ((by < 4) ? by : 11 - by) : by;
  const int b = bh >> 4, h = bh & 15;
  const int qbase = qt * 128 + w * 32;
  const int ktDiag = qbase >> 6;

  bf16x8 qf[2][2];
#pragma unroll
  for (int g = 0; g < 2; g++)
#pragma unroll
    for (int hf = 0; hf < 2; hf++) {
      int row = qbase + g * 16 + r15;
      qf[g][hf] = *(const bf16x8*)(Qm + ((size_t)(row * 4 + b)) * 1024 + h * 64 +
                                   hf * 32 + g4 * 8);
    }

  const size_t kvbase = (size_t)bh * 65536;
  const int nkt = (MODE == 0) ? (2 * qt + 2) : 14;

  f32x4 o[2][4];
#pragma unroll
  for (int g = 0; g < 2; g++)
#pragma unroll
    for (int ni = 0; ni < 4; ni++) o[g][ni] = (f32x4){0.f, 0.f, 0.f, 0.f};
  float mrun[2][4], lrun[2][4];
#pragma unroll
  for (int g = 0; g < 2; g++)
#pragma unroll
    for (int r = 0; r < 4; r++) { mrun[g][r] = -1e30f; lrun[g][r] = 0.f; }

  {
    const size_t tb = kvbase;
#pragma unroll
    for (int i = 0; i < 2; i++) {
      g2l16(Kg + tb + (size_t)(i * 256 + tid) * 8, &Kl[0][(i * 256 + w * 64) * 8]);
      g2l16(Vg + tb + (size_t)(i * 256 + tid) * 8, &Vl[0][(i * 256 + w * 64) * 8]);
    }
  }
  __syncthreads();

  for (int kt = 0; kt < nkt; kt++) {
    const int cur = kt & 1;
    if (kt + 1 < nkt) {
      const size_t tb = kvbase + (size_t)(kt + 1) * 4096;
#pragma unroll
      for (int i = 0; i < 2; i++) {
        g2l16(Kg + tb + (size_t)(i * 256 + tid) * 8,
              &Kl[cur ^ 1][(i * 256 + w * 64) * 8]);
        g2l16(Vg + tb + (size_t)(i * 256 + tid) * 8,
              &Vl[cur ^ 1][(i * 256 + w * 64) * 8]);
      }
    }

    const bool active = (MODE == 1) || (kt * 64 <= qbase + 31);
    if (active) {
      bf16x8 kb[4][2];
#pragma unroll
      for (int ni = 0; ni < 4; ni++) {
        int row = ni * 16 + r15;
        kb[ni][0] = *(const bf16x8*)(&Kl[cur][row * 64 + ((g4 ^ (row & 7)) << 3)]);
        kb[ni][1] =
            *(const bf16x8*)(&Kl[cur][row * 64 + (((g4 + 4) ^ (row & 7)) << 3)]);
      }
      f32x4 sf[2][4];
#pragma unroll
      for (int g = 0; g < 2; g++)
#pragma unroll
        for (int ni = 0; ni < 4; ni++) {
          f32x4 s = (f32x4){0.f, 0.f, 0.f, 0.f};
          s = __builtin_amdgcn_mfma_f32_16x16x32_bf16(qf[g][0], kb[ni][0], s, 0, 0, 0);
          s = __builtin_amdgcn_mfma_f32_16x16x32_bf16(qf[g][1], kb[ni][1], s, 0, 0, 0);
          sf[g][ni] = s;
        }
      if (MODE == 0 && kt >= ktDiag) {
#pragma unroll
        for (int g = 0; g < 2; g++)
#pragma unroll
          for (int ni = 0; ni < 4; ni++)
#pragma unroll
            for (int r = 0; r < 4; r++) {
              int q = qbase + g * 16 + g4 * 4 + r;
              int key = kt * 64 + ni * 16 + r15;
              if (key > q) sf[g][ni][r] = -1e30f;
            }
      }
#pragma unroll
      for (int g = 0; g < 2; g++) {
        float corr[4];
#pragma unroll
        for (int r = 0; r < 4; r++) {
          float m = fmaxf(fmaxf(sf[g][0][r], sf[g][1][r]),
                          fmaxf(sf[g][2][r], sf[g][3][r]));
          m = fmaxf(m, __shfl_xor(m, 1));
          m = fmaxf(m, __shfl_xor(m, 2));
          m = fmaxf(m, __shfl_xor(m, 4));
          m = fmaxf(m, __shfl_xor(m, 8));
          float mn = fmaxf(mrun[g][r], m);
          corr[r] = __expf(mrun[g][r] - mn);
          mrun[g][r] = mn;
        }
        float rs[4] = {0.f, 0.f, 0.f, 0.f};
#pragma unroll
        for (int ni = 0; ni < 4; ni++)
#pragma unroll
          for (int r = 0; r < 4; r++) {
            float p = __expf(sf[g][ni][r] - mrun[g][r]);
            sf[g][ni][r] = p;
            rs[r] += p;
          }
#pragma unroll
        for (int r = 0; r < 4; r++) {
          rs[r] += __shfl_xor(rs[r], 1);
          rs[r] += __shfl_xor(rs[r], 2);
          rs[r] += __shfl_xor(rs[r], 4);
          rs[r] += __shfl_xor(rs[r], 8);
          lrun[g][r] = lrun[g][r] * corr[r] + rs[r];
        }
#pragma unroll
        for (int ni = 0; ni < 4; ni++)
#pragma unroll
          for (int r = 0; r < 4; r++) o[g][ni][r] *= corr[r];
#pragma unroll
        for (int ni = 0; ni < 4; ni++)
#pragma unroll
          for (int r = 0; r < 4; r++) {
            int qr = g * 16 + g4 * 4 + r;
            int key = ni * 16 + r15;
            Pl[w][qr * 64 + ((((key >> 3) ^ ((qr >> 1) & 7)) << 3) | (key & 7))] =
                f2bf(sf[g][ni][r]);
          }
      }
#pragma unroll
      for (int kk = 0; kk < 2; kk++) {
        int gw = kk * 4 + g4;
        bf16x8 pa0 = *(const bf16x8*)(&Pl[w][r15 * 64 + ((gw ^ ((r15 >> 1) & 7)) << 3)]);
        bf16x8 pa1 =
            *(const bf16x8*)(&Pl[w][(16 + r15) * 64 + ((gw ^ ((r15 >> 1) & 7)) << 3)]);
#pragma unroll
        for (int ni = 0; ni < 4; ni++) {
          bf16x8 vb = *(const bf16x8*)(&Vl[cur][(gw * 64 + ni * 16 + r15) * 8]);
          o[0][ni] = __builtin_amdgcn_mfma_f32_16x16x32_bf16(pa0, vb, o[0][ni], 0, 0, 0);
          o[1][ni] = __builtin_amdgcn_mfma_f32_16x16x32_bf16(pa1, vb, o[1][ni], 0, 0, 0);
        }
      }
    }
    __syncthreads();
  }

#pragma unroll
  for (int g = 0; g < 2; g++) {
    float inv[4];
#pragma unroll
    for (int r = 0; r < 4; r++) inv[r] = 1.f / lrun[g][r];
#pragma unroll
    for (int ni = 0; ni < 4; ni++) {
      int col = h * 64 + ni * 16 + r15;
#pragma unroll
      for (int r = 0; r < 4; r++) {
        int tg = qbase + g * 16 + g4 * 4 + r;
        Om[((size_t)(tg * 4 + b)) * 1024 + col] = f2bf(o[g][ni][r] * inv[r]);
      }
    }
  }
}

// ---------------------------------------------------------------------------
// LayerNorm over D=1024; optional fp32 out, bf16 normed out, bf16 raw-x out.
// ---------------------------------------------------------------------------
__global__ __launch_bounds__(256) void ln_k(const float* __restrict__ x,
                                            const float* __restrict__ gw,
                                            const float* __restrict__ bw,
                                            float* __restrict__ outF,
                                            short* __restrict__ outB,
                                            short* __restrict__ outXB) {
  const int row = blockIdx.x, tid = threadIdx.x;
  const float4 v = ((const float4*)(x + (size_t)row * 1024))[tid];
  float s = v.x + v.y + v.z + v.w;
  float ss = v.x * v.x + v.y * v.y + v.z * v.z + v.w * v.w;
#pragma unroll
  for (int d = 32; d >= 1; d >>= 1) {
    s += __shfl_xor(s, d);
    ss += __shfl_xor(ss, d);
  }
  __shared__ float red[8];
  const int w = tid >> 6;
  if ((tid & 63) == 0) { red[w] = s; red[4 + w] = ss; }
  __syncthreads();
  s = red[0] + red[1] + red[2] + red[3];
  ss = red[4] + red[5] + red[6] + red[7];
  const float mean = s * (1.f / 1024.f);
  const float var = ss * (1.f / 1024.f) - mean * mean;
  const float rstd = rsqrtf(var + 1e-5f);
  const float4 gv = ((const float4*)gw)[tid];
  const float4 bv = ((const float4*)bw)[tid];
  float4 y;
  y.x = (v.x - mean) * rstd * gv.x + bv.x;
  y.y = (v.y - mean) * rstd * gv.y + bv.y;
  y.z = (v.z - mean) * rstd * gv.z + bv.z;
  y.w = (v.w - mean) * rstd * gv.w + bv.w;
  if (outF) ((float4*)(outF + (size_t)row * 1024))[tid] = y;
  if (outB) {
    short4 ob;
    ob.x = f2bf(y.x); ob.y = f2bf(y.y); ob.z = f2bf(y.z); ob.w = f2bf(y.w);
    ((short4*)(outB + (size_t)row * 1024))[tid] = ob;
  }
  if (outXB) {
    short4 ob;
    ob.x = f2bf(v.x); ob.y = f2bf(v.y); ob.z = f2bf(v.z); ob.w = f2bf(v.w);
    ((short4*)(outXB + (size_t)row * 1024))[tid] = ob;
  }
}

// ---------------------------------------------------------------------------
// Fused prep: all 8 weight transposes (fp32 [K][N] -> bf16 [N][K]) plus the
// enc_out fp32->bf16 cast, in ONE launch (8192 blocks).
// ---------------------------------------------------------------------------
__global__ __launch_bounds__(256) void prep_k(
    const float* __restrict__ Wq1, const float* __restrict__ Wkv1,
    const float* __restrict__ Wo1, const float* __restrict__ Wq2,
    const float* __restrict__ Wkv2, const float* __restrict__ Wo2,
    const float* __restrict__ Wff1, const float* __restrict__ Wff2,
    const float* __restrict__ enc,
    short* __restrict__ q1t, short* __restrict__ kv1t, short* __restrict__ o1t,
    short* __restrict__ q2t, short* __restrict__ kv2t, short* __restrict__ o2t,
    short* __restrict__ ff1t, short* __restrict__ ff2t, short* __restrict__ ebf) {
  const int id = blockIdx.x;
  const int tid = threadIdx.x;
  if (id >= 4096) {
    const size_t i = (size_t)(id - 4096) * 256 + tid;
    const float4 v = ((const float4*)enc)[i];
    short4 ob;
    ob.x = f2bf(v.x); ob.y = f2bf(v.y); ob.z = f2bf(v.z); ob.w = f2bf(v.w);
    ((short4*)ebf)[i] = ob;
    return;
  }
  const float* in;
  short* out;
  int K, N, base;
  if (id < 256)       { in = Wq1;  out = q1t;  K = 1024; N = 1024; base = 0; }
  else if (id < 768)  { in = Wkv1; out = kv1t; K = 1024; N = 2048; base = 256; }
  else if (id < 1024) { in = Wo1;  out = o1t;  K = 1024; N = 1024; base = 768; }
  else if (id < 1280) { in = Wq2;  out = q2t;  K = 1024; N = 1024; base = 1024; }
  else if (id < 1792) { in = Wkv2; out = kv2t; K = 1024; N = 2048; base = 1280; }
  else if (id < 2048) { in = Wo2;  out = o2t;  K = 1024; N = 1024; base = 1792; }
  else if (id < 3072) { in = Wff1; out = ff1t; K = 1024; N = 4096; base = 2048; }
  else                { in = Wff2; out = ff2t; K = 4096; N = 1024; base = 3072; }
  const int lid = id - base;
  const int nkb = K >> 6;
  const int k0 = (lid % nkb) * 64;
  const int n0 = (lid / nkb) * 64;

  __shared__ float t[64][65];
#pragma unroll
  for (int i = 0; i < 16; i++) {
    int flat = i * 256 + tid;
    int r = flat >> 6, c = flat & 63;
    t[r][c] = in[(size_t)(k0 + r) * N + n0 + c];
  }
  __syncthreads();
#pragma unroll
  for (int i = 0; i < 16; i++) {
    int flat = i * 256 + tid;
    int r = flat >> 6, c = flat & 63;
    out[(size_t)(n0 + r) * K + k0 + c] = f2bf(t[c][r]);
  }
}

extern "C" void kernel_launch(void* const* d_in, const int* in_sizes, int n_in,
                              void* d_out, int out_size, void* d_ws, size_t ws_size,
                              hipStream_t stream) {
  const float* dec_inp = (const float*)d_in[0];
  const float* enc_out = (const float*)d_in[1];
  const float* W_q1 = (const float*)d_in[4];
  const float* W_kv1 = (const float*)d_in[5];
  const float* W_o1 = (const float*)d_in[6];
  const float* g1 = (const float*)d_in[7];
  const float* b1 = (const float*)d_in[8];
  const float* W_q2 = (const float*)d_in[9];
  const float* W_kv2 = (const float*)d_in[10];
  const float* W_o2 = (const float*)d_in[11];
  const float* g2 = (const float*)d_in[12];
  const float* b2 = (const float*)d_in[13];
  const float* W_ff1 = (const float*)d_in[14];
  const float* b_ff1 = (const float*)d_in[15];
  const float* W_ff2 = (const float*)d_in[16];
  const float* b_ff2 = (const float*)d_in[17];
  const float* g3 = (const float*)d_in[18];
  const float* b3 = (const float*)d_in[19];
  float* out = (float*)d_out;

  char* ws = (char*)d_ws;
  size_t off = 0;
  auto alloc = [&](size_t bytes) -> void* {
    void* p = ws + off;
    off += (bytes + 255) & ~(size_t)255;
    return p;
  };
  short* Wq1t = (short*)alloc(1024ull * 1024 * 2);
  short* Wkv1t = (short*)alloc(2048ull * 1024 * 2);
  short* Wo1t = (short*)alloc(1024ull * 1024 * 2);
  short* Wq2t = (short*)alloc(1024ull * 1024 * 2);
  short* Wkv2t = (short*)alloc(2048ull * 1024 * 2);
  short* Wo2t = (short*)alloc(1024ull * 1024 * 2);
  short* Wff1t = (short*)alloc(4096ull * 1024 * 2);
  short* Wff2t = (short*)alloc(1024ull * 4096 * 2);
  short* Xbf = (short*)alloc((size_t)NTOK * 1024 * 2);
  short* Ebf = (short*)alloc((size_t)NTOK * 1024 * 2);
  short* Cbf = (short*)alloc((size_t)NTOK * 1024 * 2);
  short* Qb = (short*)alloc((size_t)NTOK * 1024 * 2);
  short* Kg = (short*)alloc(64ull * 65536 * 2);
  short* Vg = (short*)alloc(64ull * 65536 * 2);
  short* VECb = (short*)alloc((size_t)NTOK * 1024 * 2);
  float* OUT1 = (float*)alloc((size_t)NTOK * 1024 * 4);
  float* H2f = (float*)alloc((size_t)NTOK * 1024 * 4);
  float* OUT2 = (float*)alloc((size_t)NTOK * 1024 * 4);
  short* FF1 = (short*)alloc((size_t)NTOK * 4096 * 2);
  short* H2b = Xbf;  // Xbf dead after qkv1
  short* H3b = Cbf;  // Cbf dead after qkv1

  dim3 blk(256, 1, 1);

  // all weight transposes + enc cast in one launch
  prep_k<<<8192, blk, 0, stream>>>(W_q1, W_kv1, W_o1, W_q2, W_kv2, W_o2, W_ff1,
                                   W_ff2, enc_out, Wq1t, Wkv1t, Wo1t, Wq2t,
                                   Wkv2t, Wo2t, Wff1t, Wff2t, Ebf);
  // LN(dec_inp) -> Cbf (bf16) and raw dec_inp -> Xbf (bf16) in one pass
  ln_k<<<4096, blk, 0, stream>>>(dec_inp, g1, b1, nullptr, Cbf, Xbf);

  // ---- self attention ----
  qkv_k<<<dim3(32, 48), blk, 0, stream>>>(Xbf, Wq1t, Qb, Cbf, Wkv1t, Kg, Vg);
  attn_k2<0><<<dim3(64, 8), blk, 0, stream>>>(Qb, Kg, Vg, VECb);
  gemm_bt<1, 64><<<dim3(32, 16), blk, 0, stream>>>(
      VECb, Wo1t, OUT1, nullptr, dec_inp, nullptr, 4096, 1024, 1024);
  // ---- cross attention ----
  ln_k<<<4096, blk, 0, stream>>>(OUT1, g2, b2, H2f, H2b, nullptr);
  qkv_k<<<dim3(32, 48), blk, 0, stream>>>(H2b, Wq2t, Qb, Ebf, Wkv2t, Kg, Vg);
  attn_k2<1><<<dim3(64, 8), blk, 0, stream>>>(Qb, Kg, Vg, VECb);
  gemm_bt<1, 64><<<dim3(32, 16), blk, 0, stream>>>(
      VECb, Wo2t, OUT2, nullptr, H2f, nullptr, 4096, 1024, 1024);
  // ---- FFN ----
  ln_k<<<4096, blk, 0, stream>>>(OUT2, g3, b3, nullptr, H3b, nullptr);
  gemm8p<2><<<dim3(16, 16), dim3(512, 1, 1), 0, stream>>>(
      H3b, Wff1t, nullptr, FF1, nullptr, b_ff1, 4096, 4096, 1024);
  gemm_bt<3, 64><<<dim3(32, 16), blk, 0, stream>>>(
      FF1, Wff2t, out, nullptr, OUT2, b_ff2, 4096, 1024, 4096);
}